// Round 5
// baseline (424.142 us; speedup 1.0000x reference)
//
#include <hip/hip_runtime.h>

typedef short bf16x8 __attribute__((ext_vector_type(8)));
typedef float f32x4 __attribute__((ext_vector_type(4)));

#define NBLK 512

__device__ __forceinline__ unsigned short f2bf(float f) {
    unsigned u = __float_as_uint(f);
    u += 0x7FFFu + ((u >> 16) & 1u);      // round-to-nearest-even
    return (unsigned short)(u >> 16);
}
__device__ __forceinline__ void gload_lds16(const void* g, void* l) {
    __builtin_amdgcn_global_load_lds(
        (const __attribute__((address_space(1))) void*)g,
        (__attribute__((address_space(3))) void*)l,
        16, 0, 0);
}

// Software grid barrier. SAFE because: grid=512 blocks at __launch_bounds__(256,2)
// => exactly 2 blocks/CU x 256 CUs, all co-resident by capacity (LDS 26.7KB, VGPR<=256
// forced by LB). Device-scope atomics + __threadfence per G16. Counters pre-zeroed
// by hipMemsetAsync node (ws is poisoned 0xAA before every call).
__device__ __forceinline__ void gbar(unsigned* cnt) {
    __syncthreads();
    if (threadIdx.x == 0) {
        __threadfence();
        __hip_atomic_fetch_add(cnt, 1u, __ATOMIC_ACQ_REL, __HIP_MEMORY_SCOPE_AGENT);
        while (__hip_atomic_load(cnt, __ATOMIC_ACQUIRE, __HIP_MEMORY_SCOPE_AGENT) < NBLK)
            __builtin_amdgcn_s_sleep(2);
        __threadfence();
    }
    __syncthreads();
}

// ---------------------------------------------------------------- mega-kernel
// phase0: u -> bf16 A' (rows permuted: A'[p*128+b*16+ll] = u[b*2048+p*16+ll]);
//         Bt (interleaved 16-wide r/i col groups), Dt (matching k-order, -Ci).
// phase1: GEMM1 128x256 tile; mid-barrier; fused phase+batch-cumsum epilogue
//         writes X bf16 (standard rows b*2048+l) INTO A's buffer (A dead after bar).
// phase2: GEMM2 -> y fp32.
__global__ __launch_bounds__(256, 2)
void lru_mega(const float* __restrict__ u, const int* __restrict__ len,
              const float* __restrict__ nu_log, const float* __restrict__ th_log,
              const float* __restrict__ Br, const float* __restrict__ Bi,
              const float* __restrict__ Cr, const float* __restrict__ Ci,
              unsigned short* __restrict__ A, unsigned short* __restrict__ Bt,
              unsigned short* __restrict__ Dt, float* __restrict__ Y,
              unsigned* __restrict__ cnt) {
    __shared__ unsigned short As[128 * 32];   // 8 KB
    __shared__ unsigned short Bs[256 * 32];   // 16 KB (fp32 totals in epilogue)
    __shared__ unsigned short tile[32][33];   // 2.1 KB (phase0 transpose)

    const int tid = threadIdx.x;
    const int bid = blockIdx.x;

    // ================= phase 0: prep =================
    for (int it = 0; it < 32; ++it) {
        int i = (bid * 32 + it) * 256 + tid;    // float4 id, A'-order
        int ro = i >> 8, c4 = i & 255;
        int p = ro >> 7, b = (ro >> 4) & 7, ll = ro & 15;
        int ri = b * 2048 + p * 16 + ll;        // source row in u
        float4 v = ((const float4*)u)[(size_t)ri * 256 + c4];
        ushort4 o; o.x = f2bf(v.x); o.y = f2bf(v.y); o.z = f2bf(v.z); o.w = f2bf(v.w);
        ((ushort4*)A)[i] = o;
    }
    {
        int tx = tid & 31, ty = tid >> 5;       // 32 x 8
        for (int q = 0; q < 4; ++q) {
            int id2 = q * NBLK + bid;           // [0, 2048)
            int z = id2 >> 10, t = id2 & 1023;
            int jt = t >> 5, kt = t & 31;
            __syncthreads();
            if (z == 0) {
                for (int i2 = ty; i2 < 32; i2 += 8) {       // i2 = k offset
                    int k = kt * 32 + i2;
                    float v = (tx < 16) ? Br[(size_t)k * 512 + jt * 16 + tx]
                                        : Bi[(size_t)k * 512 + jt * 16 + (tx & 15)];
                    tile[tx][i2] = f2bf(v);                 // tile[w][k]
                }
                __syncthreads();
                for (int i2 = ty; i2 < 32; i2 += 8)         // i2 = w
                    Bt[(size_t)(jt * 32 + i2) * 1024 + kt * 32 + tx] = tile[i2][tx];
            } else {
                for (int i2 = ty; i2 < 32; i2 += 8) {       // i2 = w
                    float v = (i2 < 16) ? Cr[(size_t)(jt * 16 + i2) * 1024 + kt * 32 + tx]
                                        : -Ci[(size_t)(jt * 16 + (i2 & 15)) * 1024 + kt * 32 + tx];
                    tile[i2][tx] = f2bf(v);                 // tile[w][h]
                }
                __syncthreads();
                for (int i2 = ty; i2 < 32; i2 += 8)         // i2 = h offset
                    Dt[(size_t)(kt * 32 + i2) * 1024 + jt * 32 + tx] = tile[tx][i2];
            }
        }
    }
    gbar(cnt + 0);

    // ================= common wave geometry =================
    const int wave = tid >> 6, lane = tid & 63;
    const int lm = lane & 15, lq = lane >> 4;
    const int wr = wave >> 1, wc = wave & 1;
    const int xcd = bid & 7, j = bid >> 3;
    const int o = tid * 16;

    // ================= phase 1: GEMM1 =================
    {
        const int p    = xcd * 16 + (j >> 2);   // l-panel
        const int row0 = p * 128;
        const int col0 = (j & 3) * 256;

        f32x4 acc[4][8] = {};
        const char* gA0 = (const char*)A  + (size_t)(row0 + (o >> 6)) * 2048 + (o & 63);
        const char* gA1 = gA0 + 64 * 2048;
        const char* gB0 = (const char*)Bt + (size_t)(col0 + (o >> 6)) * 2048 + (o & 63);
        const char* gB1 = gB0 + 64 * 2048;
        const char* gB2 = gB1 + 64 * 2048;
        const char* gB3 = gB2 + 64 * 2048;
        char* lA0 = (char*)As + wave * 1024; char* lA1 = lA0 + 4096;
        char* lB0 = (char*)Bs + wave * 1024; char* lB1 = lB0 + 4096;
        char* lB2 = lB1 + 4096;              char* lB3 = lB2 + 4096;

        for (int kk = 0; kk < 32; ++kk) {
            __syncthreads();
            gload_lds16(gA0, lA0); gload_lds16(gA1, lA1);
            gload_lds16(gB0, lB0); gload_lds16(gB1, lB1);
            gload_lds16(gB2, lB2); gload_lds16(gB3, lB3);
            gA0 += 64; gA1 += 64; gB0 += 64; gB1 += 64; gB2 += 64; gB3 += 64;
            __syncthreads();

            bf16x8 af[4], bfr[8];
#pragma unroll
            for (int mi = 0; mi < 4; ++mi) {
                int m = wr * 64 + mi * 16 + lm;
                af[mi] = *(const bf16x8*)(As + m * 32 + lq * 8);
            }
#pragma unroll
            for (int ni = 0; ni < 8; ++ni) {
                int n = wc * 128 + ni * 16 + lm;
                bfr[ni] = *(const bf16x8*)(Bs + n * 32 + lq * 8);
            }
#pragma unroll
            for (int mi = 0; mi < 4; ++mi)
#pragma unroll
                for (int ni = 0; ni < 8; ++ni)
                    acc[mi][ni] = __builtin_amdgcn_mfma_f32_16x16x32_bf16(
                        af[mi], bfr[ni], acc[mi][ni], 0, 0, 0);
        }

        // all blocks done reading A => X may overwrite A's buffer
        gbar(cnt + 1);

        unsigned short* X = A;
        float* tot = (float*)Bs;
        const float inv2pi = 0.15915494309189535f;
        const float twopi  = 6.283185307179586f;

        int lenv[8];
#pragma unroll
        for (int b = 0; b < 8; ++b) lenv[b] = len[b];
        float nuv[4], rvv[4];
#pragma unroll
        for (int g = 0; g < 4; ++g) {
            int n = (col0 >> 1) + wc * 64 + g * 16 + lm;
            nuv[g] = __expf(nu_log[n]);
            rvv[g] = __expf(th_log[n]) * inv2pi;
        }
        const int l_lo = p * 16 + lq * 4;

        if (wr == 0) {
#pragma unroll
            for (int g = 0; g < 4; ++g) {
#pragma unroll
                for (int r = 0; r < 4; ++r) {
                    float sr = 0.f, si = 0.f;
                    int l = l_lo + r;
                    float lp1 = (float)(l + 1);
#pragma unroll
                    for (int mi = 0; mi < 4; ++mi) {
                        int b = mi;
                        float e = fmaxf((float)lenv[b] - lp1, 0.f);
                        float mag = __expf(-e * nuv[g]);
                        float ar = e * rvv[g]; ar -= floorf(ar);
                        float sn, cs; __sincosf(ar * twopi, &sn, &cs);
                        float Lr = mag * cs, Li = mag * sn;
                        float Bur = acc[mi][2 * g][r], Bui = acc[mi][2 * g + 1][r];
                        sr += Lr * Bur - Li * Bui;
                        si += Lr * Bui + Li * Bur;
                        size_t rowoff = ((size_t)b * 2048 + l) * 1024;
                        int c = col0 + wc * 128 + g * 32 + lm;
                        X[rowoff + c]      = f2bf(sr);
                        X[rowoff + c + 16] = f2bf(si);
                    }
                    int f = (g * 4 + r) * 2;
                    tot[(wc * 32 + f) * 64 + lane]     = sr;
                    tot[(wc * 32 + f + 1) * 64 + lane] = si;
                }
            }
        }
        __syncthreads();
        if (wr == 1) {
#pragma unroll
            for (int g = 0; g < 4; ++g) {
#pragma unroll
                for (int r = 0; r < 4; ++r) {
                    int f = (g * 4 + r) * 2;
                    float sr = tot[(wc * 32 + f) * 64 + lane];
                    float si = tot[(wc * 32 + f + 1) * 64 + lane];
                    int l = l_lo + r;
                    float lp1 = (float)(l + 1);
#pragma unroll
                    for (int mi = 0; mi < 4; ++mi) {
                        int b = 4 + mi;
                        float e = fmaxf((float)lenv[b] - lp1, 0.f);
                        float mag = __expf(-e * nuv[g]);
                        float ar = e * rvv[g]; ar -= floorf(ar);
                        float sn, cs; __sincosf(ar * twopi, &sn, &cs);
                        float Lr = mag * cs, Li = mag * sn;
                        float Bur = acc[mi][2 * g][r], Bui = acc[mi][2 * g + 1][r];
                        sr += Lr * Bur - Li * Bui;
                        si += Lr * Bui + Li * Bur;
                        size_t rowoff = ((size_t)b * 2048 + l) * 1024;
                        int c = col0 + wc * 128 + g * 32 + lm;
                        X[rowoff + c]      = f2bf(sr);
                        X[rowoff + c + 16] = f2bf(si);
                    }
                }
            }
        }
    }
    gbar(cnt + 2);

    // ================= phase 2: GEMM2 =================
    {
        const unsigned short* X = A;            // standard rows b*2048+l
        const int row0 = (xcd * 16 + (j >> 2)) * 128;
        const int col0 = (j & 3) * 256;

        f32x4 acc[4][8] = {};
        const char* gA0 = (const char*)X  + (size_t)(row0 + (o >> 6)) * 2048 + (o & 63);
        const char* gA1 = gA0 + 64 * 2048;
        const char* gB0 = (const char*)Dt + (size_t)(col0 + (o >> 6)) * 2048 + (o & 63);
        const char* gB1 = gB0 + 64 * 2048;
        const char* gB2 = gB1 + 64 * 2048;
        const char* gB3 = gB2 + 64 * 2048;
        char* lA0 = (char*)As + wave * 1024; char* lA1 = lA0 + 4096;
        char* lB0 = (char*)Bs + wave * 1024; char* lB1 = lB0 + 4096;
        char* lB2 = lB1 + 4096;              char* lB3 = lB2 + 4096;

        for (int kk = 0; kk < 32; ++kk) {
            __syncthreads();
            gload_lds16(gA0, lA0); gload_lds16(gA1, lA1);
            gload_lds16(gB0, lB0); gload_lds16(gB1, lB1);
            gload_lds16(gB2, lB2); gload_lds16(gB3, lB3);
            gA0 += 64; gA1 += 64; gB0 += 64; gB1 += 64; gB2 += 64; gB3 += 64;
            __syncthreads();

            bf16x8 af[4], bfr[8];
#pragma unroll
            for (int mi = 0; mi < 4; ++mi) {
                int m = wr * 64 + mi * 16 + lm;
                af[mi] = *(const bf16x8*)(As + m * 32 + lq * 8);
            }
#pragma unroll
            for (int ni = 0; ni < 8; ++ni) {
                int n = wc * 128 + ni * 16 + lm;
                bfr[ni] = *(const bf16x8*)(Bs + n * 32 + lq * 8);
            }
#pragma unroll
            for (int mi = 0; mi < 4; ++mi)
#pragma unroll
                for (int ni = 0; ni < 8; ++ni)
                    acc[mi][ni] = __builtin_amdgcn_mfma_f32_16x16x32_bf16(
                        af[mi], bfr[ni], acc[mi][ni], 0, 0, 0);
        }

#pragma unroll
        for (int mi = 0; mi < 4; ++mi) {
#pragma unroll
            for (int ni = 0; ni < 8; ++ni) {
                int c  = col0 + wc * 128 + ni * 16 + lm;
                int r0 = row0 + wr * 64 + mi * 16 + lq * 4;
#pragma unroll
                for (int r = 0; r < 4; ++r)
                    Y[(size_t)(r0 + r) * 1024 + c] = acc[mi][ni][r];
            }
        }
    }
}

// ----------------------------------------------------------------
extern "C" void kernel_launch(void* const* d_in, const int* in_sizes, int n_in,
                              void* d_out, int out_size, void* d_ws, size_t ws_size,
                              hipStream_t stream) {
    const float* u      = (const float*)d_in[0];   // (8,2048,1024) f32
    const int*   len    = (const int*)d_in[1];     // (8,)
    const float* nu_log = (const float*)d_in[2];   // (512,)
    const float* th_log = (const float*)d_in[3];   // (512,)
    const float* Br     = (const float*)d_in[4];   // (1024,512)
    const float* Bi     = (const float*)d_in[5];   // (1024,512)
    const float* Cr     = (const float*)d_in[6];   // (512,1024)
    const float* Ci     = (const float*)d_in[7];   // (512,1024)
    float* y = (float*)d_out;                      // (8,2048,1024) f32

    char* ws = (char*)d_ws;
    unsigned short* A  = (unsigned short*)(ws);                 // 33.5 MB (A', then X in place)
    unsigned short* Bt = (unsigned short*)(ws + 33554432);      //  2 MB
    unsigned short* Dt = (unsigned short*)(ws + 35651584);      //  2 MB
    unsigned*       cn = (unsigned*)(ws + 37748736);            //  3 barrier counters

    hipMemsetAsync(cn, 0, 128, stream);
    lru_mega<<<NBLK, 256, 0, stream>>>(u, len, nu_log, th_log, Br, Bi, Cr, Ci,
                                       A, Bt, Dt, y, cn);
}